// Round 9
// baseline (262.550 us; speedup 1.0000x reference)
//
#include <hip/hip_runtime.h>

#define TPB 1024

typedef _Float16 hf2 __attribute__((ext_vector_type(2)));

__device__ __forceinline__ hf2 as_h2(unsigned u) { return __builtin_bit_cast(hf2, u); }
__device__ __forceinline__ unsigned pk2h(float a, float b) {
    unsigned la = (unsigned)__builtin_bit_cast(unsigned short, (_Float16)a);
    unsigned hb = (unsigned)__builtin_bit_cast(unsigned short, (_Float16)b);
    return la | (hb << 16);
}
#define FDOT2(w, x, acc) __builtin_amdgcn_fdot2(as_h2(w), as_h2(x), (acc), false)

// Cross-lane adds OFF the DS pipe (VALU DPP): xor1 = quad_perm 0xB1,
// xor2 = quad_perm 0x4E, xor8 = row_ror:8 (0x128). xor4 has no DPP -> ds_swizzle.
#define DPPADD(v, CTRL) ((v) + __int_as_float(__builtin_amdgcn_update_dpp( \
    0, __float_as_int(v), (CTRL), 0xF, 0xF, false)))
#define SWZADD(v, OFF) ((v) + __int_as_float(__builtin_amdgcn_ds_swizzle( \
    __float_as_int(v), (OFF))))
#define RED4(v)  { v = DPPADD(v, 0xB1); v = DPPADD(v, 0x4E); }
#define RED16(v) { v = DPPADD(v, 0xB1); v = DPPADD(v, 0x4E); \
                   v = SWZADD(v, 0x101F); v = DPPADD(v, 0x128); }

#define RED64(v) { v += __shfl_xor(v,32,64); v += __shfl_xor(v,16,64); \
  v += __shfl_xor(v,8,64); v += __shfl_xor(v,4,64); v += __shfl_xor(v,2,64); \
  v += __shfl_xor(v,1,64); }

#define G4(M) M(0) M(1) M(2) M(3)

// r5/r8 post-mortem: both are DS-instruction-issue bound (384 wave-DS/CU/eval
// x ~12cyc = measured 4600cyc/eval; broadcasts cost full rate). This version
// cuts DS to ~166/CU/eval:
//  - thread covers 32 rows x 2 cols in BOTH matvecs -> operand reads halve
//    (4 x b128 broadcast per phase), each read feeds 8 fdot2
//  - W1 AND W2 in registers (32+32 packed-f16-pair u32; TPB=1024 hard-caps
//    VGPR at 128 -- budget ~115, watch WRITE_SIZE for spill)
//  - cross-thread dot reduction via VALU DPP (xor1/xor2/xor8) + 1 ds_swizzle
//  - k-history/state replicated in registers of the 16 lanes sharing an
//    output pair -> no part[]/kx[] arrays, 2 barriers/eval (was 3)
//  - trace/KL: thread-local accumulators, one block reduce at the end
__global__ __launch_bounds__(TPB, 1) void vi_node_kernel(
    const float* __restrict__ x0, const float* __restrict__ W1,
    const float* __restrict__ b1, const float* __restrict__ u1,
    const float* __restrict__ W2, const float* __restrict__ b2,
    const int* __restrict__ nsp, float* __restrict__ out, int nB)
{
    const int s  = blockIdx.x;
    const int t  = threadIdx.x;
    const int l  = t & 63;
    const int w  = t >> 6;            // wave 0..15
    const int rg    = l & 3;          // H row-group: rows 32*rg .. 32*rg+31 (of 128)
    const int cpair = 16 * w + (l >> 2);  // H col-pair 0..255 -> cols 2cp, 2cp+1
    const int c0 = 2 * cpair, c1 = c0 + 1;
    const int rg4   = l & 15;         // P row-group: rows 32*rg4 .. +31 (of 512)
    const int jpair = 4 * w + (l >> 4);   // P col-pair 0..63 -> cols 2jp, 2jp+1
    const int j0 = 2 * jpair, j1 = j0 + 1;

    __shared__ __align__(16) unsigned xsPK[64];   // x, f16 pairs (pair k = elems 2k,2k+1)
    __shared__ __align__(16) unsigned aPKp[320];  // tanh acts, padded: pair k -> (k>>4)*20+(k&15)
    __shared__ float redA[16], redB[16], sqred[2];

    // ---- persistent W registers: f16 pairs, named scalars ----
#define DECLW(cc) unsigned wA##cc##_0, wA##cc##_1, wA##cc##_2, wA##cc##_3, \
                           wB##cc##_0, wB##cc##_1, wB##cc##_2, wB##cc##_3; \
                  unsigned zA##cc##_0, zA##cc##_1, zA##cc##_2, zA##cc##_3, \
                           zB##cc##_0, zB##cc##_1, zB##cc##_2, zB##cc##_3;
    G4(DECLW)

    // W1 pairs: reg (cc,m) = rows 32rg+2(4cc+m), +1 of col c0 (wA) / c1 (wB)
#define LDW1(cc) { const int r_ = 32 * rg + 8 * (cc); \
    wA##cc##_0 = pk2h(W1[(r_+0)*512+c0], W1[(r_+1)*512+c0]); \
    wA##cc##_1 = pk2h(W1[(r_+2)*512+c0], W1[(r_+3)*512+c0]); \
    wA##cc##_2 = pk2h(W1[(r_+4)*512+c0], W1[(r_+5)*512+c0]); \
    wA##cc##_3 = pk2h(W1[(r_+6)*512+c0], W1[(r_+7)*512+c0]); \
    wB##cc##_0 = pk2h(W1[(r_+0)*512+c1], W1[(r_+1)*512+c1]); \
    wB##cc##_1 = pk2h(W1[(r_+2)*512+c1], W1[(r_+3)*512+c1]); \
    wB##cc##_2 = pk2h(W1[(r_+4)*512+c1], W1[(r_+5)*512+c1]); \
    wB##cc##_3 = pk2h(W1[(r_+6)*512+c1], W1[(r_+7)*512+c1]); }
    G4(LDW1)

    // W2 pairs: reg (cc,m) = rows 32rg4+2(4cc+m), +1 of col j0 (zA) / j1 (zB)
#define LDW2(cc) { const int r_ = 32 * rg4 + 8 * (cc); \
    zA##cc##_0 = pk2h(W2[(r_+0)*128+j0], W2[(r_+1)*128+j0]); \
    zA##cc##_1 = pk2h(W2[(r_+2)*128+j0], W2[(r_+3)*128+j0]); \
    zA##cc##_2 = pk2h(W2[(r_+4)*128+j0], W2[(r_+5)*128+j0]); \
    zA##cc##_3 = pk2h(W2[(r_+6)*128+j0], W2[(r_+7)*128+j0]); \
    zB##cc##_0 = pk2h(W2[(r_+0)*128+j1], W2[(r_+1)*128+j1]); \
    zB##cc##_1 = pk2h(W2[(r_+2)*128+j1], W2[(r_+3)*128+j1]); \
    zB##cc##_2 = pk2h(W2[(r_+4)*128+j1], W2[(r_+5)*128+j1]); \
    zB##cc##_3 = pk2h(W2[(r_+6)*128+j1], W2[(r_+7)*128+j1]); }
    G4(LDW2)

    // ---- wdiag for H cols (exact fp32): partial over this thread's 32 i's ----
    float wd0 = 0.f, wd1 = 0.f;
#pragma unroll
    for (int i = 0; i < 32; ++i) {
        const int r_ = 32 * rg + i;
        wd0 = fmaf(W1[r_ * 512 + c0], W2[c0 * 128 + r_], wd0);
        wd1 = fmaf(W1[r_ * 512 + c1], W2[c1 * 128 + r_], wd1);
    }
    RED4(wd0) RED4(wd1)

    const float b1k0 = b1[c0], b1k1 = b1[c1];
    const float u1k0 = u1[c0], u1k1 = u1[c1];
    const float b2j0 = b2[j0], b2j1 = b2[j1];

    const int ns = nsp[0];
    const float dt = 1.f / (float)ns;

    // ---- init: xsPK, sumsq, register state ----
    if (t < 64) xsPK[t] = pk2h(x0[s * 128 + 2 * t], x0[s * 128 + 2 * t + 1]);
    if (t < 128) {
        float xv = x0[s * 128 + t];
        float sq = xv * xv;
        RED64(sq)
        if (l == 0) sqred[w] = sq;
    }
    float xc0 = x0[s * 128 + j0], xc1 = x0[s * 128 + j1];   // replicated x16
    float yc0 = xc0, yc1 = xc1;
    float k0_0=0.f,k0_1=0.f,k1_0=0.f,k1_1=0.f,k2_0=0.f,k2_1=0.f,
          k3_0=0.f,k3_1=0.f,k4_0=0.f,k4_1=0.f;
    float tr_loc = 0.f, dot_loc = 0.f;
    __syncthreads();

    // ---- per-eval compute groups ----
#define HM(cc) { const uint4 xq = *(const uint4*)&xsPK[16 * rg + 4 * (cc)]; \
    a0 = FDOT2(wA##cc##_0, xq.x, a0); a1 = FDOT2(wA##cc##_1, xq.y, a1); \
    a0 = FDOT2(wA##cc##_2, xq.z, a0); a1 = FDOT2(wA##cc##_3, xq.w, a1); \
    b0 = FDOT2(wB##cc##_0, xq.x, b0); b1v = FDOT2(wB##cc##_1, xq.y, b1v); \
    b0 = FDOT2(wB##cc##_2, xq.z, b0); b1v = FDOT2(wB##cc##_3, xq.w, b1v); }

#define PM(cc) { const uint4 aq = *(const uint4*)&aPKp[20 * rg4 + 4 * (cc)]; \
    p0 = FDOT2(zA##cc##_0, aq.x, p0); p1 = FDOT2(zA##cc##_1, aq.y, p1); \
    p0 = FDOT2(zA##cc##_2, aq.z, p0); p1 = FDOT2(zA##cc##_3, aq.w, p1); \
    q0 = FDOT2(zB##cc##_0, aq.x, q0); q1 = FDOT2(zB##cc##_1, aq.y, q1); \
    q0 = FDOT2(zB##cc##_2, aq.z, q0); q1 = FDOT2(zB##cc##_3, aq.w, q1); }

// One RHS eval + state advance. 2 barriers. CW = dopri B-weight of this stage.
#define EVAL(CW, TVAL, KST0, KST1, XN0, XN1, LAST)                             \
    {                                                                          \
        float a0=0.f, a1=0.f, b0=0.f, b1v=0.f;                                 \
        HM(0) HM(1) HM(2) HM(3)                                                \
        float sA = a0 + a1, sB = b0 + b1v;                                     \
        RED4(sA) RED4(sB)                        /* sum over rg (4 lanes) */   \
        float h0 = fmaf((TVAL), u1k0, b1k0) + sA;                              \
        float h1 = fmaf((TVAL), u1k1, b1k1) + sB;                              \
        float aa0 = 1.f - 2.f / (__expf(2.f * h0) + 1.f);                      \
        float aa1 = 1.f - 2.f / (__expf(2.f * h1) + 1.f);                      \
        if (rg == 0)                                                           \
            aPKp[(cpair >> 4) * 20 + (cpair & 15)] = pk2h(aa0, aa1);           \
        tr_loc = fmaf((CW), fmaf(-aa0, aa0, 1.f) * wd0                         \
                          + fmaf(-aa1, aa1, 1.f) * wd1, tr_loc);               \
        __syncthreads();                          /* B1: aPKp ready */         \
        float p0=0.f, p1=0.f, q0=0.f, q1=0.f;                                  \
        PM(0) PM(1) PM(2) PM(3)                                                \
        float sp = p0 + p1, sq_ = q0 + q1;                                     \
        RED16(sp) RED16(sq_)                      /* sum over rg4 (16 lanes) */\
        float dx0 = sp + b2j0, dx1 = sq_ + b2j1;                               \
        dot_loc = fmaf((CW), xc0 * dx0 + xc1 * dx1, dot_loc);                  \
        KST0; KST1;                                                            \
        xc0 = (XN0); xc1 = (XN1);                                              \
        if (LAST) { yc0 = xc0; yc1 = xc1; }                                    \
        if ((l & 15) == 0) xsPK[jpair] = pk2h(xc0, xc1);                       \
        __syncthreads();                          /* B2: xsPK ready */         \
    }

    for (int n = 0; n < ns; ++n) {
        const float tn = (float)n;

        EVAL((float)(35.0/384.0), tn * dt, k0_0 = dx0, k0_1 = dx1,
             fmaf(dt, 0.2f * dx0, yc0), fmaf(dt, 0.2f * dx1, yc1), 0)

        EVAL(0.0f, (tn + 0.2f) * dt, k1_0 = dx0, k1_1 = dx1,
             yc0 + dt * (0.075f * k0_0 + 0.225f * dx0),
             yc1 + dt * (0.075f * k0_1 + 0.225f * dx1), 0)

        EVAL((float)(500.0/1113.0), (tn + 0.3f) * dt, k2_0 = dx0, k2_1 = dx1,
             yc0 + dt * ((float)(44.0/45.0) * k0_0 + (float)(-56.0/15.0) * k1_0
                       + (float)(32.0/9.0)  * dx0),
             yc1 + dt * ((float)(44.0/45.0) * k0_1 + (float)(-56.0/15.0) * k1_1
                       + (float)(32.0/9.0)  * dx1), 0)

        EVAL((float)(125.0/192.0), (tn + 0.8f) * dt, k3_0 = dx0, k3_1 = dx1,
             yc0 + dt * ((float)(19372.0/6561.0) * k0_0 + (float)(-25360.0/2187.0) * k1_0
                       + (float)(64448.0/6561.0) * k2_0 + (float)(-212.0/729.0)    * dx0),
             yc1 + dt * ((float)(19372.0/6561.0) * k0_1 + (float)(-25360.0/2187.0) * k1_1
                       + (float)(64448.0/6561.0) * k2_1 + (float)(-212.0/729.0)    * dx1), 0)

        EVAL((float)(-2187.0/6784.0), (tn + (float)(8.0/9.0)) * dt, k4_0 = dx0, k4_1 = dx1,
             yc0 + dt * ((float)(9017.0/3168.0)  * k0_0 + (float)(-355.0/33.0) * k1_0
                       + (float)(46732.0/5247.0) * k2_0 + (float)(49.0/176.0)  * k3_0
                       + (float)(-5103.0/18656.0) * dx0),
             yc1 + dt * ((float)(9017.0/3168.0)  * k0_1 + (float)(-355.0/33.0) * k1_1
                       + (float)(46732.0/5247.0) * k2_1 + (float)(49.0/176.0)  * k3_1
                       + (float)(-5103.0/18656.0) * dx1), 0)

        EVAL((float)(11.0/84.0), (tn + 1.0f) * dt, (void)0, (void)0,
             yc0 + dt * ((float)(35.0/384.0)  * k0_0 + (float)(500.0/1113.0)   * k2_0
                       + (float)(125.0/192.0) * k3_0 + (float)(-2187.0/6784.0) * k4_0
                       + (float)(11.0/84.0)   * dx0),
             yc1 + dt * ((float)(35.0/384.0)  * k0_1 + (float)(500.0/1113.0)   * k2_1
                       + (float)(125.0/192.0) * k3_1 + (float)(-2187.0/6784.0) * k4_1
                       + (float)(11.0/84.0)   * dx1), 1)
    }

    // ---- final reductions (once): tr (x4 replicated), dot (x16 replicated) ----
    {
        float tv = tr_loc;  RED64(tv)  if (l == 0) redA[w] = tv;
        float dv = dot_loc; RED64(dv)  if (l == 0) redB[w] = dv;
    }
    __syncthreads();

    // ---- outputs: z (B,D) | log_px (B) | kl (B) ----
    if ((l & 15) == 0) {
        out[s * 128 + j0] = yc0;
        out[s * 128 + j1] = yc1;
    }
    if (t == 0) {
        float TRs = 0.f, DOs = 0.f;
#pragma unroll
        for (int ww = 0; ww < 16; ++ww) { TRs += redA[ww]; DOs += redB[ww]; }
        const float TR = TRs * dt * 0.25f;          // 4x lane replication
        const float DO = DOs * dt * (1.f / 16.f);   // 16x lane replication
        const float LOG2PI = 1.8378770664093454f;
        float lpx0 = -0.5f * (sqred[0] + sqred[1]) - 0.5f * 128.f * LOG2PI;
        out[nB * 128 + s]      = lpx0 - TR;
        out[nB * 128 + nB + s] = DO - TR;
    }
}

extern "C" void kernel_launch(void* const* d_in, const int* in_sizes, int n_in,
                              void* d_out, int out_size, void* d_ws, size_t ws_size,
                              hipStream_t stream) {
    const float* x0 = (const float*)d_in[0];
    const float* W1 = (const float*)d_in[1];
    const float* b1 = (const float*)d_in[2];
    const float* u1 = (const float*)d_in[3];
    const float* W2 = (const float*)d_in[4];
    const float* b2 = (const float*)d_in[5];
    const int*  nsp = (const int*)d_in[6];
    float* out = (float*)d_out;
    const int nB = in_sizes[0] / 128;   // 128 samples

    hipLaunchKernelGGL(vi_node_kernel, dim3(nB), dim3(TPB), 0, stream,
                       x0, W1, b1, u1, W2, b2, nsp, out, nB);
}